// Round 4
// baseline (766.427 us; speedup 1.0000x reference)
//
#include <hip/hip_runtime.h>

constexpr int BB = 4096;   // batch
constexpr int TT = 2048;   // time
constexpr int HH = 32;     // hidden

typedef float v2f __attribute__((ext_vector_type(2)));
typedef float v4f __attribute__((ext_vector_type(4)));
typedef _Float16 v2h __attribute__((ext_vector_type(2)));

// ---------- fast math (v_exp_f32 / v_rcp_f32) ----------
__device__ __forceinline__ float fexp2(float x) { return __builtin_amdgcn_exp2f(x); }
__device__ __forceinline__ float frcp(float x)  { return __builtin_amdgcn_rcpf(x); }
__device__ __forceinline__ float fsigmoid(float x) {
    return frcp(1.0f + fexp2(x * -1.4426950408889634f));
}
__device__ __forceinline__ float felu(float x) {
    return x > 0.0f ? x : (fexp2(x * 1.4426950408889634f) - 1.0f);
}

// ---------- kernel 1: counting sort of batch indices by length, descending ----------
__global__ void sort_by_len_kernel(const int* __restrict__ lengths, int* __restrict__ perm) {
    __shared__ int hist[TT];     // key = TT - len  in [0, TT-1]
    __shared__ int csum[256];
    const int tid = threadIdx.x;
    for (int i = tid; i < TT; i += 256) hist[i] = 0;
    __syncthreads();
    for (int i = tid; i < BB; i += 256) atomicAdd(&hist[TT - lengths[i]], 1);
    __syncthreads();
    const int base = tid * 8;
    int loc[8];
    int s = 0;
#pragma unroll
    for (int j = 0; j < 8; ++j) { loc[j] = hist[base + j]; s += loc[j]; }
    csum[tid] = s;
    __syncthreads();
    for (int off = 1; off < 256; off <<= 1) {
        int v = (tid >= off) ? csum[tid - off] : 0;
        __syncthreads();
        csum[tid] += v;
        __syncthreads();
    }
    int run = csum[tid] - s;
#pragma unroll
    for (int j = 0; j < 8; ++j) { int t = loc[j]; hist[base + j] = run; run += t; }
    __syncthreads();
    for (int i = tid; i < BB; i += 256) {
        int pos = atomicAdd(&hist[TT - lengths[i]], 1);
        perm[pos] = i;
    }
}

// ---------- kernel 2: backward LSTM + MLP head ----------
// ISOLATION ROUND: r2's per-step arithmetic BIT-EXACT (same dot order, same
// s0/s1/v1 activation forms, unscaled c, real __shfl_xor for ig, same f16
// conversions) -> absmax must be exactly 1.953125e-3. The only changes vs r2
// are bit-exact data movement:
//   - h allgather: lane 32+2j packs (h[2j],h[2j+1]) via DPP quad_perm + f16
//     pack, 16 v_readlane -> wave-uniform pairs feed v_dot2 directly.
//     Replaces the h LDS round-trip (~240 cy of wave-local stall chain).
//   - x broadcast: chunk of 64 in a VGPR (coalesced load, prefetched 1 ahead),
//     per-step v_readlane with wave-uniform index. Replaces xbuf LDS.
// Complement chaining kept: wave k does sorted rank k then BB-1-k (2048 waves,
// 2/SIMD flat, ~TT+1 steps each). Zero LDS in this kernel.
// Lane layout (unit n = lane&31): lower lane n owns rows (i=n, g=64+n) -> ig;
// upper lane 32+n owns rows (f=32+n, o=96+n) -> c, h.
__global__ __attribute__((amdgpu_flat_work_group_size(64, 64)))
void lstm_kernel(const float* __restrict__ x, const int* __restrict__ lengths,
                 const float* __restrict__ w_ih, const float* __restrict__ w_hh,
                 const float* __restrict__ b_ih, const float* __restrict__ b_hh,
                 const float* __restrict__ fc_w, const float* __restrict__ fc_b,
                 const float* __restrict__ fc2_w, const float* __restrict__ fc2_b,
                 float* __restrict__ out, const int* __restrict__ perm) {
    const int lane = threadIdx.x;       // 0..63
    const int r0 = lane;        // i (lower) / f (upper)
    const int r1 = lane + 64;   // g (lower) / o (upper)

    const bool  lower  = lane < 32;
    const float NL2E   = -1.4426950408889634f;
    const float scale0 = NL2E;                           // i/f: sigmoid
    const float scale1 = lower ? 2.0f * NL2E : NL2E;     // g: tanh, o: sigmoid
    const float amul   = lower ? 2.0f : 1.0f;
    const float badd   = lower ? -1.0f : 0.0f;

    // per-lane pre-scaled f16 weights in registers (32 VGPRs), shared by both phases
    v2h w0[16], w1[16];
    {
        const v2f* p0 = reinterpret_cast<const v2f*>(w_hh + r0 * 32);
        const v2f* p1 = reinterpret_cast<const v2f*>(w_hh + r1 * 32);
#pragma unroll
        for (int q = 0; q < 16; ++q) {
            v2f a = p0[q]; v2f bq = p1[q];
            w0[q] = (v2h){(_Float16)(a.x * scale0), (_Float16)(a.y * scale0)};
            w1[q] = (v2h){(_Float16)(bq.x * scale1), (_Float16)(bq.y * scale1)};
        }
    }
    const float wi0 = w_ih[r0] * scale0;
    const float wi1 = w_ih[r1] * scale1;
    const float bi0 = (b_ih[r0] + b_hh[r0]) * scale0;
    const float bi1 = (b_ih[r1] + b_hh[r1]) * scale1;

    // anti-remat pin
#pragma unroll
    for (int q = 0; q < 16; ++q) {
        asm volatile("" : "+v"(w0[q]), "+v"(w1[q]));
    }

    for (int phase = 0; phase < 2; ++phase) {
        const int k = phase ? (BB - 1 - (int)blockIdx.x) : (int)blockIdx.x;
        const int b = perm ? perm[k] : k;
        const int L = lengths[b];
        const float* xb = x + (size_t)b * TT;

        int hp[16];                       // wave-uniform packed h pairs
#pragma unroll
        for (int j = 0; j < 16; ++j) hp[j] = 0;
        float c = 0.0f;

        int t = L - 1;
        int tb = t & ~63;
        float xv = xb[tb + lane];         // 64 x values across lanes (coalesced)
        while (t >= 0) {
            const int tbn = tb - 64;
            float xvn = 0.0f;
            if (tbn >= 0) xvn = xb[tbn + lane];   // prefetch next chunk
            const int xvi = __builtin_bit_cast(int, xv);
            for (; t >= tb; --t) {
                const float xt = __builtin_bit_cast(float,
                    __builtin_amdgcn_readlane(xvi, t - tb));
                float a0  = fmaf(wi0, xt, bi0);
                float a1  = fmaf(wi1, xt, bi1);
                float a0b = 0.0f, a1b = 0.0f;
#pragma unroll
                for (int q = 0; q < 16; q += 2) {
                    const v2h pA = __builtin_bit_cast(v2h, hp[q]);
                    const v2h pB = __builtin_bit_cast(v2h, hp[q + 1]);
                    a0  = __builtin_amdgcn_fdot2(w0[q],     pA, a0,  false);
                    a0b = __builtin_amdgcn_fdot2(w0[q + 1], pB, a0b, false);
                    a1  = __builtin_amdgcn_fdot2(w1[q],     pA, a1,  false);
                    a1b = __builtin_amdgcn_fdot2(w1[q + 1], pB, a1b, false);
                }
                const float g0 = a0 + a0b;     // pre-scaled gate inputs
                const float g1 = a1 + a1b;
                const float s0 = frcp(1.0f + fexp2(g0));   // sig(i) / sig(f)
                const float s1 = frcp(1.0f + fexp2(g1));
                const float v1 = fmaf(amul, s1, badd);     // tanh(g) / sig(o)
                const float ig = s0 * v1;                  // lower: i*g (upper: junk)
                const float igx = __shfl_xor(ig, 32);      // exact exchange (DS pipe)
                // upper lanes own c:  c = f*c + i*g
                c = fmaf(s0, c, igx);
                const float tc = 1.0f - 2.0f * frcp(1.0f + fexp2(c * 2.8853900817779268f));
                const float hn = v1 * tc;                  // upper: sig(o)*tanh(c)
                // pack neighbor pair: lane 32+2j ends with (h[2j], h[2j+1])
                const int hni = __builtin_bit_cast(int, hn);
                const int hxi = __builtin_amdgcn_update_dpp(
                    0, hni, 0xB1 /*quad_perm(1,0,3,2)*/, 0xF, 0xF, false);
                const v2h pk = {(_Float16)hn,
                                (_Float16)__builtin_bit_cast(float, hxi)};
                const int pki = __builtin_bit_cast(int, pk);
#pragma unroll
                for (int j = 0; j < 16; ++j)
                    hp[j] = __builtin_amdgcn_readlane(pki, 32 + 2 * j);
            }
            xv = xvn;
            tb = tbn;
        }

        // ---- head: out[b] = sigmoid( sum_r fc2_w[r]*elu(fc_w[r]@h + fc_b[r]) + fc2_b ) ----
        float hf[32];
#pragma unroll
        for (int j = 0; j < 16; ++j) {
            const v2h p = __builtin_bit_cast(v2h, hp[j]);
            hf[2 * j]     = (float)p[0];
            hf[2 * j + 1] = (float)p[1];
        }
        float a = fc_b[lane];
        {
            const v4f* fp = reinterpret_cast<const v4f*>(fc_w + lane * 32);
#pragma unroll
            for (int q = 0; q < 8; ++q) {
                const v4f f = fp[q];
                a = fmaf(f.x, hf[4 * q + 0], a);
                a = fmaf(f.y, hf[4 * q + 1], a);
                a = fmaf(f.z, hf[4 * q + 2], a);
                a = fmaf(f.w, hf[4 * q + 3], a);
            }
        }
        float partial = felu(a) * fc2_w[lane];
#pragma unroll
        for (int m = 32; m >= 1; m >>= 1) partial += __shfl_xor(partial, m, 64);
        if (lane == 0) out[b] = fsigmoid(partial + fc2_b[0]);
    }
}

extern "C" void kernel_launch(void* const* d_in, const int* in_sizes, int n_in,
                              void* d_out, int out_size, void* d_ws, size_t ws_size,
                              hipStream_t stream) {
    const float* x       = (const float*)d_in[0];
    const int*   lengths = (const int*)d_in[1];
    const float* w_ih    = (const float*)d_in[2];
    const float* w_hh    = (const float*)d_in[3];
    const float* b_ih    = (const float*)d_in[4];
    const float* b_hh    = (const float*)d_in[5];
    const float* fc_w    = (const float*)d_in[6];
    const float* fc_b    = (const float*)d_in[7];
    const float* fc2_w   = (const float*)d_in[8];
    const float* fc2_b   = (const float*)d_in[9];
    float* out = (float*)d_out;

    int* perm = nullptr;
    if (ws_size >= (size_t)BB * sizeof(int)) {
        perm = (int*)d_ws;
        hipLaunchKernelGGL(sort_by_len_kernel, dim3(1), dim3(256), 0, stream, lengths, perm);
    }
    hipLaunchKernelGGL(lstm_kernel, dim3(BB / 2), dim3(64), 0, stream,
                       x, lengths, w_ih, w_hh, b_ih, b_hh,
                       fc_w, fc_b, fc2_w, fc2_b, out, perm);
}

// Round 5
// 676.617 us; speedup vs baseline: 1.1327x; 1.1327x over previous
//
#include <hip/hip_runtime.h>

constexpr int BB = 4096;   // batch
constexpr int TT = 2048;   // time
constexpr int HH = 32;     // hidden
constexpr int GE = 16;     // elements per block (MFMA N)

typedef float v4f __attribute__((ext_vector_type(4)));
typedef float f32x4 __attribute__((ext_vector_type(4)));
typedef _Float16 f16x8 __attribute__((ext_vector_type(8)));
typedef _Float16 v2h __attribute__((ext_vector_type(2)));
typedef _Float16 v8h __attribute__((ext_vector_type(8)));

// ---------- fast math ----------
__device__ __forceinline__ float fexp2(float x) { return __builtin_amdgcn_exp2f(x); }
__device__ __forceinline__ float frcp(float x)  { return __builtin_amdgcn_rcpf(x); }
__device__ __forceinline__ float fsigmoid(float x) {
    return frcp(1.0f + fexp2(x * -1.4426950408889634f));
}
__device__ __forceinline__ float felu(float x) {
    return x > 0.0f ? x : (fexp2(x * 1.4426950408889634f) - 1.0f);
}

// ---------- kernel 1: counting sort of batch indices by length, descending ----------
__global__ void sort_by_len_kernel(const int* __restrict__ lengths, int* __restrict__ perm) {
    __shared__ int hist[TT];
    __shared__ int csum[256];
    const int tid = threadIdx.x;
    for (int i = tid; i < TT; i += 256) hist[i] = 0;
    __syncthreads();
    for (int i = tid; i < BB; i += 256) atomicAdd(&hist[TT - lengths[i]], 1);
    __syncthreads();
    const int base = tid * 8;
    int loc[8];
    int s = 0;
#pragma unroll
    for (int j = 0; j < 8; ++j) { loc[j] = hist[base + j]; s += loc[j]; }
    csum[tid] = s;
    __syncthreads();
    for (int off = 1; off < 256; off <<= 1) {
        int v = (tid >= off) ? csum[tid - off] : 0;
        __syncthreads();
        csum[tid] += v;
        __syncthreads();
    }
    int run = csum[tid] - s;
#pragma unroll
    for (int j = 0; j < 8; ++j) { int t = loc[j]; hist[base + j] = run; run += t; }
    __syncthreads();
    for (int i = tid; i < BB; i += 256) {
        int pos = atomicAdd(&hist[TT - lengths[i]], 1);
        perm[pos] = i;
    }
}

// ---------- kernel 2: MFMA group-batched backward LSTM + MLP head ----------
// r0-r4 established: any 1-element-per-wave structure pays a ~500cy/step serial
// chain (4 dependent transcendentals + exchange) that occupancy cannot hide
// (flat occupancy provably capped at 2 waves/SIMD by the longest element).
// This kernel amortizes that chain over 16 elements:
//   - 256 blocks x 4 waves; block g owns sorted elements perm[16g..16g+15]
//     (adjacent sorted ranks -> near-equal lengths; shorter ones predicated).
//   - Per step, gates(128x16) = W(128x32) @ h(32x16) via 2 MFMAs per wave
//     (mfma_f32_16x16x32_f16). Wave w covers units 8w..8w+7. MFMA m's 16 A-rows
//     are interleaved (i,f,g,o) of units {8w+2q+m, q=0..3}, so D (col=lane&15,
//     row=4*(lane>>4)+i) hands each lane the COMPLETE 4-gate set of unit
//     u_m = 8w+2*(lane>>4)+m for element e=lane&15: cell update is lane-local,
//     zero cross-lane ops. K-dim lane mapping is contraction-symmetric, so A
//     and B only need the SAME k permutation (both use k = 8*(lane>>4)+j).
//   - bias + w_ih*x enter as the MFMA C operand (free adds).
//   - h: f16 in LDS [2][16 el][40 pad], double-buffered, ONE barrier per step.
//   - A rows pre-scaled (-log2e sigmoid rows, -2log2e tanh row); activations
//     use r1's precision-proven fused forms; tanh(c) keeps r2's exact form.
__global__ __attribute__((amdgpu_flat_work_group_size(256, 256)))
void lstm_kernel(const float* __restrict__ x, const int* __restrict__ lengths,
                 const float* __restrict__ w_ih, const float* __restrict__ w_hh,
                 const float* __restrict__ b_ih, const float* __restrict__ b_hh,
                 const float* __restrict__ fc_w, const float* __restrict__ fc_b,
                 const float* __restrict__ fc2_w, const float* __restrict__ fc2_b,
                 float* __restrict__ out, const int* __restrict__ perm) {
    __shared__ __align__(16) _Float16 hb[2][GE][40];  // h, f16, padded rows
    __shared__ __align__(16) float xls[GE][68];       // x chunk, padded rows
    __shared__ int barr[GE];
    __shared__ int Llds[GE];
    __shared__ int maxLs;

    const int tid  = threadIdx.x;
    const int wv   = tid >> 6;        // wave 0..3
    const int lane = tid & 63;
    const int lg   = lane >> 4;       // lane group 0..3
    const int e    = lane & 15;       // element (MFMA col) for B/D

    const int g = blockIdx.x;
    if (tid < GE) {
        const int b = perm ? perm[GE * g + tid] : (GE * g + tid);
        barr[tid] = b;
        Llds[tid] = lengths[b];
    }
    for (int i = tid; i < 2 * GE * 40; i += 256) ((_Float16*)hb)[i] = (_Float16)0.0f;
    __syncthreads();
    if (tid == 0) {
        int m = 0;
        for (int i = 0; i < GE; ++i) m = max(m, Llds[i]);
        maxLs = m;
    }
    __syncthreads();
    const int maxL = maxLs;
    const int Lme  = Llds[e];

    const float NL2E = -1.4426950408889634f;

    // ---- A fragments (loaded once). A row r = lane&15 -> (q = r>>2, gate s = r&3);
    // MFMA m covers unit u = 8*wv + 2*q + m; W row = s*32 + u; k = 8*lg + j.
    const int r = lane & 15;
    const int sgate = r & 3;
    const int qq = r >> 2;
    const float asc = (sgate == 2) ? 2.0f * NL2E : NL2E;  // g row: tanh scaling
    f16x8 afr[2];
#pragma unroll
    for (int m = 0; m < 2; ++m) {
        const int u = 8 * wv + 2 * qq + m;
        const int wrow = sgate * 32 + u;
        const v4f* wp = reinterpret_cast<const v4f*>(w_hh + wrow * 32 + 8 * lg);
        const v4f wa = wp[0], wb = wp[1];
        afr[m] = (f16x8){(_Float16)(wa.x * asc), (_Float16)(wa.y * asc),
                         (_Float16)(wa.z * asc), (_Float16)(wa.w * asc),
                         (_Float16)(wb.x * asc), (_Float16)(wb.y * asc),
                         (_Float16)(wb.z * asc), (_Float16)(wb.w * asc)};
    }
    // ---- per-lane D-row constants: D rows are gates i=0..3 of unit 8*wv+2*lg+m
    float wih_[2][4], bs_[2][4];
#pragma unroll
    for (int m = 0; m < 2; ++m) {
        const int u = 8 * wv + 2 * lg + m;
#pragma unroll
        for (int i = 0; i < 4; ++i) {
            const float scd = (i == 2) ? 2.0f * NL2E : NL2E;
            wih_[m][i] = w_ih[i * 32 + u] * scd;
            bs_[m][i]  = (b_ih[i * 32 + u] + b_hh[i * 32 + u]) * scd;
        }
    }

    float c0 = 0.0f, c1 = 0.0f;
    int p = 0;
    const int hoff = 8 * wv + 2 * lg;     // write slot (units u0, u0+1)

    for (int s = maxL - 1; s >= 0; --s) {
        if (s == maxL - 1 || (s & 63) == 63) {
            // stage x chunk [tb, tb+63] for all 16 elements (coalesced)
            const int tb = s & ~63;
            const int es = tid >> 4, j4 = (tid & 15) * 4;
            const float* xp = x + (size_t)barr[es] * TT + tb + j4;
            *reinterpret_cast<v4f*>(&xls[es][j4]) = *reinterpret_cast<const v4f*>(xp);
            __syncthreads();
        }
        // B fragment: h[k = 8*lg + j][e], contiguous 16B
        const f16x8 bf = *reinterpret_cast<const f16x8*>(&hb[p][e][lg * 8]);
        const float xe = xls[e][s & 63];
        f32x4 C0, C1;
#pragma unroll
        for (int i = 0; i < 4; ++i) {
            C0[i] = fmaf(wih_[0][i], xe, bs_[0][i]);
            C1[i] = fmaf(wih_[1][i], xe, bs_[1][i]);
        }
        const f32x4 D0 = __builtin_amdgcn_mfma_f32_16x16x32_f16(afr[0], bf, C0, 0, 0, 0);
        const f32x4 D1 = __builtin_amdgcn_mfma_f32_16x16x32_f16(afr[1], bf, C1, 0, 0, 0);
        const bool act = (s < Lme);

        // ---- cell update, unit m=0 (r1-proven fused forms, r2 tanh-c form)
        float h0, h1;
        {
            const float Ei = fexp2(D0[0]), Ef = fexp2(D0[1]);
            const float Eg = fexp2(D0[2]), Eo = fexp2(D0[3]);
            const float R1 = frcp((1.0f + Ei) * (1.0f + Eg));
            const float ig = (1.0f - Eg) * R1;
            const float R2 = frcp((1.0f + Ef) * (1.0f + Eo));
            const float sf = (1.0f + Eo) * R2;
            const float so = (1.0f + Ef) * R2;
            const float cn = fmaf(sf, c0, ig);
            c0 = act ? cn : c0;
            const float tc = 1.0f - 2.0f * frcp(1.0f + fexp2(c0 * 2.8853900817779268f));
            h0 = act ? (so * tc) : 0.0f;
        }
        {
            const float Ei = fexp2(D1[0]), Ef = fexp2(D1[1]);
            const float Eg = fexp2(D1[2]), Eo = fexp2(D1[3]);
            const float R1 = frcp((1.0f + Ei) * (1.0f + Eg));
            const float ig = (1.0f - Eg) * R1;
            const float R2 = frcp((1.0f + Ef) * (1.0f + Eo));
            const float sf = (1.0f + Eo) * R2;
            const float so = (1.0f + Ef) * R2;
            const float cn = fmaf(sf, c1, ig);
            c1 = act ? cn : c1;
            const float tc = 1.0f - 2.0f * frcp(1.0f + fexp2(c1 * 2.8853900817779268f));
            h1 = act ? (so * tc) : 0.0f;
        }
        // write h[u0][e], h[u0+1][e] as one dword (u0 = 8*wv+2*lg, even)
        const v2h pk = {(_Float16)h0, (_Float16)h1};
        *reinterpret_cast<v2h*>(&hb[p ^ 1][e][hoff]) = pk;
        __syncthreads();
        p ^= 1;
    }

    // ---- head: wave w handles elements 4w..4w+3 (r2's proven per-element math)
    for (int e2 = 4 * wv; e2 < 4 * wv + 4; ++e2) {
        float hf[32];
        const v8h* hp8 = reinterpret_cast<const v8h*>(&hb[p][e2][0]);
#pragma unroll
        for (int q4 = 0; q4 < 4; ++q4) {
            const v8h hh = hp8[q4];
#pragma unroll
            for (int j = 0; j < 8; ++j) hf[8 * q4 + j] = (float)hh[j];
        }
        float a = fc_b[lane];
        const v4f* fp = reinterpret_cast<const v4f*>(fc_w + lane * 32);
#pragma unroll
        for (int q4 = 0; q4 < 8; ++q4) {
            const v4f f = fp[q4];
            a = fmaf(f.x, hf[4 * q4 + 0], a);
            a = fmaf(f.y, hf[4 * q4 + 1], a);
            a = fmaf(f.z, hf[4 * q4 + 2], a);
            a = fmaf(f.w, hf[4 * q4 + 3], a);
        }
        float partial = felu(a) * fc2_w[lane];
#pragma unroll
        for (int m = 32; m >= 1; m >>= 1) partial += __shfl_xor(partial, m, 64);
        if (lane == 0) out[barr[e2]] = fsigmoid(partial + fc2_b[0]);
    }
}

extern "C" void kernel_launch(void* const* d_in, const int* in_sizes, int n_in,
                              void* d_out, int out_size, void* d_ws, size_t ws_size,
                              hipStream_t stream) {
    const float* x       = (const float*)d_in[0];
    const int*   lengths = (const int*)d_in[1];
    const float* w_ih    = (const float*)d_in[2];
    const float* w_hh    = (const float*)d_in[3];
    const float* b_ih    = (const float*)d_in[4];
    const float* b_hh    = (const float*)d_in[5];
    const float* fc_w    = (const float*)d_in[6];
    const float* fc_b    = (const float*)d_in[7];
    const float* fc2_w   = (const float*)d_in[8];
    const float* fc2_b   = (const float*)d_in[9];
    float* out = (float*)d_out;

    int* perm = nullptr;
    if (ws_size >= (size_t)BB * sizeof(int)) {
        perm = (int*)d_ws;
        hipLaunchKernelGGL(sort_by_len_kernel, dim3(1), dim3(256), 0, stream, lengths, perm);
    }
    hipLaunchKernelGGL(lstm_kernel, dim3(BB / GE), dim3(256), 0, stream,
                       x, lengths, w_ih, w_hh, b_ih, b_hh,
                       fc_w, fc_b, fc2_w, fc2_b, out, perm);
}

// Round 6
// 614.574 us; speedup vs baseline: 1.2471x; 1.1010x over previous
//
#include <hip/hip_runtime.h>

constexpr int BB = 4096;   // batch
constexpr int TT = 2048;   // time
constexpr int HH = 32;     // hidden
constexpr int GE = 16;     // elements per block (MFMA N)

typedef float v2f __attribute__((ext_vector_type(2)));
typedef float v4f __attribute__((ext_vector_type(4)));
typedef float f32x4 __attribute__((ext_vector_type(4)));
typedef _Float16 f16x8 __attribute__((ext_vector_type(8)));
typedef _Float16 v8h __attribute__((ext_vector_type(8)));

// ---------- fast math ----------
__device__ __forceinline__ float fexp2(float x) { return __builtin_amdgcn_exp2f(x); }
__device__ __forceinline__ float frcp(float x)  { return __builtin_amdgcn_rcpf(x); }
__device__ __forceinline__ float fsigmoid(float x) {
    return frcp(1.0f + fexp2(x * -1.4426950408889634f));
}
__device__ __forceinline__ float felu(float x) {
    return x > 0.0f ? x : (fexp2(x * 1.4426950408889634f) - 1.0f);
}

// ---------- kernel 1: counting sort of batch indices by length, descending ----------
__global__ void sort_by_len_kernel(const int* __restrict__ lengths, int* __restrict__ perm) {
    __shared__ int hist[TT];
    __shared__ int csum[256];
    const int tid = threadIdx.x;
    for (int i = tid; i < TT; i += 256) hist[i] = 0;
    __syncthreads();
    for (int i = tid; i < BB; i += 256) atomicAdd(&hist[TT - lengths[i]], 1);
    __syncthreads();
    const int base = tid * 8;
    int loc[8];
    int s = 0;
#pragma unroll
    for (int j = 0; j < 8; ++j) { loc[j] = hist[base + j]; s += loc[j]; }
    csum[tid] = s;
    __syncthreads();
    for (int off = 1; off < 256; off <<= 1) {
        int v = (tid >= off) ? csum[tid - off] : 0;
        __syncthreads();
        csum[tid] += v;
        __syncthreads();
    }
    int run = csum[tid] - s;
#pragma unroll
    for (int j = 0; j < 8; ++j) { int t = loc[j]; hist[base + j] = run; run += t; }
    __syncthreads();
    for (int i = tid; i < BB; i += 256) {
        int pos = atomicAdd(&hist[TT - lengths[i]], 1);
        perm[pos] = i;
    }
}

// ---------- kernel 2: MFMA group-batched backward LSTM, 8 waves/block ----------
// r5 post-mortem: with 4 waves/block the grid is 256 blocks on 256 CUs = 1
// wave/SIMD; the ~700cy barrier-to-barrier chain (ds_read h 120 + MFMA 40 +
// trans chain 140 + write + barrier drain + un-overlapped issue) has NOTHING
// to hide it -> VALUBusy 26%, chain = wall. Makespan is structurally
// 2048 steps x wall/step (group count == CU count), so the only lever is the
// per-step critical path. This round: SAME dataflow, 8 waves/block (512 thr),
// 1 MFMA per wave, each lane does exactly ONE unit-element cell update:
//   - per-wave issue ~110cy (was ~190) -> less barrier straggle
//   - 2 waves/SIMD -> co-wave issue overlaps the chain's latency segments
// Unit map: wave w owns units 4w..4w+3. MFMA A row r: gate s=r&3, q=r>>2,
// unit u=4w+q, W row = s*32+u, k = 8*(lane>>4)+j (A and B share the same
// k-perm; contraction-symmetric). D (col=lane&15, row=4*lg+i): lane (lg,e)
// gets the complete 4-gate set of unit 4w+lg, element e. Same weights, same
// C-operand, same activation code as r5 -> D bit-identical -> absmax must
// stay exactly 1.953125e-3.
__global__ __attribute__((amdgpu_flat_work_group_size(512, 512)))
void lstm_kernel(const float* __restrict__ x, const int* __restrict__ lengths,
                 const float* __restrict__ w_ih, const float* __restrict__ w_hh,
                 const float* __restrict__ b_ih, const float* __restrict__ b_hh,
                 const float* __restrict__ fc_w, const float* __restrict__ fc_b,
                 const float* __restrict__ fc2_w, const float* __restrict__ fc2_b,
                 float* __restrict__ out, const int* __restrict__ perm) {
    __shared__ __align__(16) _Float16 hb[2][GE][40];  // h, f16, padded rows, dbuf
    __shared__ __align__(16) float xls[GE][68];       // x chunk, padded rows
    __shared__ int barr[GE];
    __shared__ int Llds[GE];
    __shared__ int maxLs;

    const int tid  = threadIdx.x;
    const int wv   = tid >> 6;        // wave 0..7
    const int lane = tid & 63;
    const int lg   = lane >> 4;       // lane group 0..3
    const int e    = lane & 15;       // element (MFMA col)

    const int g = blockIdx.x;
    if (tid < GE) {
        const int b = perm ? perm[GE * g + tid] : (GE * g + tid);
        barr[tid] = b;
        Llds[tid] = lengths[b];
    }
    for (int i = tid; i < 2 * GE * 40; i += 512) ((_Float16*)hb)[i] = (_Float16)0.0f;
    __syncthreads();
    if (tid == 0) {
        int m = 0;
        for (int i = 0; i < GE; ++i) m = max(m, Llds[i]);
        maxLs = m;
    }
    __syncthreads();
    const int maxL = maxLs;
    const int Lme  = Llds[e];

    const float NL2E = -1.4426950408889634f;

    // ---- A fragment (loaded once): row r = lane&15 -> gate s=r&3, q=r>>2,
    // unit u = 4*wv + q; W row = s*32+u; k = 8*lg + j.
    const int r  = lane & 15;
    const int sg = r & 3;
    const int ua = 4 * wv + (r >> 2);
    const float asc = (sg == 2) ? 2.0f * NL2E : NL2E;   // g row: tanh scaling
    f16x8 afr;
    {
        const v4f* wp = reinterpret_cast<const v4f*>(w_hh + (sg * 32 + ua) * 32 + 8 * lg);
        const v4f wa = wp[0], wb = wp[1];
        afr = (f16x8){(_Float16)(wa.x * asc), (_Float16)(wa.y * asc),
                      (_Float16)(wa.z * asc), (_Float16)(wa.w * asc),
                      (_Float16)(wb.x * asc), (_Float16)(wb.y * asc),
                      (_Float16)(wb.z * asc), (_Float16)(wb.w * asc)};
    }
    // ---- D-row constants: D rows are gates i=0..3 of unit ud = 4*wv + lg
    const int ud = 4 * wv + lg;
    float wih_[4], bs_[4];
#pragma unroll
    for (int i = 0; i < 4; ++i) {
        const float scd = (i == 2) ? 2.0f * NL2E : NL2E;
        wih_[i] = w_ih[i * 32 + ud] * scd;
        bs_[i]  = (b_ih[i * 32 + ud] + b_hh[i * 32 + ud]) * scd;
    }

    float c = 0.0f;
    int p = 0;

    for (int s = maxL - 1; s >= 0; --s) {
        if (s == maxL - 1 || (s & 63) == 63) {
            // stage x chunk [tb, tb+63] for all 16 elements (512 thr x 2 floats)
            const int tb = s & ~63;
            const int es = tid >> 5, j2 = (tid & 31) * 2;
            const float* xp = x + (size_t)barr[es] * TT + tb + j2;
            *reinterpret_cast<v2f*>(&xls[es][j2]) = *reinterpret_cast<const v2f*>(xp);
            __syncthreads();
        }
        // B fragment: h[k = 8*lg + j][e], contiguous 16B
        const f16x8 bf = *reinterpret_cast<const f16x8*>(&hb[p][e][lg * 8]);
        const float xe = xls[e][s & 63];
        f32x4 C;
#pragma unroll
        for (int i = 0; i < 4; ++i) C[i] = fmaf(wih_[i], xe, bs_[i]);
        const f32x4 D = __builtin_amdgcn_mfma_f32_16x16x32_f16(afr, bf, C, 0, 0, 0);
        const bool act = (s < Lme);

        // ---- cell update (r1-proven fused forms, r2 tanh-c form)
        const float Ei = fexp2(D[0]), Ef = fexp2(D[1]);
        const float Eg = fexp2(D[2]), Eo = fexp2(D[3]);
        const float R1 = frcp((1.0f + Ei) * (1.0f + Eg));
        const float ig = (1.0f - Eg) * R1;
        const float R2 = frcp((1.0f + Ef) * (1.0f + Eo));
        const float sf = (1.0f + Eo) * R2;
        const float so = (1.0f + Ef) * R2;
        const float cn = fmaf(sf, c, ig);
        c = act ? cn : c;
        const float tc = 1.0f - 2.0f * frcp(1.0f + fexp2(c * 2.8853900817779268f));
        const float hn = act ? (so * tc) : 0.0f;

        hb[p ^ 1][e][ud] = (_Float16)hn;
        __syncthreads();
        p ^= 1;
    }

    // ---- head: wave wv handles elements 2wv, 2wv+1 (r2's proven per-element math)
    for (int e2 = 2 * wv; e2 < 2 * wv + 2; ++e2) {
        float hf[32];
        const v8h* hp8 = reinterpret_cast<const v8h*>(&hb[p][e2][0]);
#pragma unroll
        for (int q4 = 0; q4 < 4; ++q4) {
            const v8h hh = hp8[q4];
#pragma unroll
            for (int j = 0; j < 8; ++j) hf[8 * q4 + j] = (float)hh[j];
        }
        float a = fc_b[lane];
        const v4f* fp = reinterpret_cast<const v4f*>(fc_w + lane * 32);
#pragma unroll
        for (int q4 = 0; q4 < 8; ++q4) {
            const v4f f = fp[q4];
            a = fmaf(f.x, hf[4 * q4 + 0], a);
            a = fmaf(f.y, hf[4 * q4 + 1], a);
            a = fmaf(f.z, hf[4 * q4 + 2], a);
            a = fmaf(f.w, hf[4 * q4 + 3], a);
        }
        float partial = felu(a) * fc2_w[lane];
#pragma unroll
        for (int m = 32; m >= 1; m >>= 1) partial += __shfl_xor(partial, m, 64);
        if (lane == 0) out[barr[e2]] = fsigmoid(partial + fc2_b[0]);
    }
}

extern "C" void kernel_launch(void* const* d_in, const int* in_sizes, int n_in,
                              void* d_out, int out_size, void* d_ws, size_t ws_size,
                              hipStream_t stream) {
    const float* x       = (const float*)d_in[0];
    const int*   lengths = (const int*)d_in[1];
    const float* w_ih    = (const float*)d_in[2];
    const float* w_hh    = (const float*)d_in[3];
    const float* b_ih    = (const float*)d_in[4];
    const float* b_hh    = (const float*)d_in[5];
    const float* fc_w    = (const float*)d_in[6];
    const float* fc_b    = (const float*)d_in[7];
    const float* fc2_w   = (const float*)d_in[8];
    const float* fc2_b   = (const float*)d_in[9];
    float* out = (float*)d_out;

    int* perm = nullptr;
    if (ws_size >= (size_t)BB * sizeof(int)) {
        perm = (int*)d_ws;
        hipLaunchKernelGGL(sort_by_len_kernel, dim3(1), dim3(256), 0, stream, lengths, perm);
    }
    hipLaunchKernelGGL(lstm_kernel, dim3(BB / GE), dim3(512), 0, stream,
                       x, lengths, w_ih, w_hh, b_ih, b_hh,
                       fc_w, fc_b, fc2_w, fc2_b, out, perm);
}